// Round 15
// baseline (373.514 us; speedup 1.0000x reference)
//
#include <hip/hip_runtime.h>

#define NN 20000
#define NE 320000

typedef __attribute__((ext_vector_type(8))) short bf16x8;
typedef __attribute__((ext_vector_type(4))) float f32x4;

__device__ __forceinline__ float bf2f(unsigned short u) {
  union { unsigned int i; float f; } v; v.i = ((unsigned int)u) << 16; return v.f;
}
__device__ __forceinline__ unsigned short f2bf(float f) {
  union { float f; unsigned int i; } v; v.f = f;
  unsigned int r = v.i + 0x7FFF + ((v.i >> 16) & 1);
  return (unsigned short)(r >> 16);
}
__device__ __forceinline__ float4 ld_bf4(const unsigned short* p) {
  ushort4 u = *(const ushort4*)p;
  float4 f;
  f.x = bf2f(u.x); f.y = bf2f(u.y); f.z = bf2f(u.z); f.w = bf2f(u.w);
  return f;
}

// ---------------- CSR construction ----------------

__global__ void zero_i32(int* __restrict__ p, int n) {
  int i = blockIdx.x * blockDim.x + threadIdx.x;
  if (i < n) p[i] = 0;
}

__global__ void count_dst(const int* __restrict__ ei, int* __restrict__ counts) {
  int e = blockIdx.x * blockDim.x + threadIdx.x;
  if (e < NE) atomicAdd(&counts[ei[NE + e]], 1);
}

__global__ void scan_local(const int* __restrict__ counts, int* __restrict__ tmp,
                           int* __restrict__ bsum) {
  __shared__ int sh[1024];
  int b = blockIdx.x, t = threadIdx.x, i = b * 1024 + t;
  int v = (i < NN) ? counts[i] : 0;
  sh[t] = v;
  __syncthreads();
  for (int off = 1; off < 1024; off <<= 1) {
    int add = (t >= off) ? sh[t - off] : 0;
    __syncthreads();
    sh[t] += add;
    __syncthreads();
  }
  if (i < NN) tmp[i] = sh[t];
  if (t == 1023) bsum[b] = sh[t];
}

__global__ void scan_bsum(int* __restrict__ bsum, int nb) {
  if (threadIdx.x == 0) {
    int run = 0;
    for (int j = 0; j < nb; ++j) { int v = bsum[j]; bsum[j] = run; run += v; }
  }
}

__global__ void scan_finish(const int* __restrict__ counts, const int* __restrict__ tmp,
                            const int* __restrict__ bsum, int* __restrict__ row_ptr,
                            int* __restrict__ cursor) {
  int i = blockIdx.x * 256 + threadIdx.x;
  if (i == 0) row_ptr[0] = 0;
  if (i < NN) {
    int incl = tmp[i] + bsum[i >> 10];
    row_ptr[i + 1] = incl;
    cursor[i] = incl - counts[i];
  }
}

__global__ void scatter_edges(const int* __restrict__ ei, const float4* __restrict__ eattr4,
                              int* __restrict__ cursor, int* __restrict__ srcs,
                              float4* __restrict__ ea_r) {
  int e = blockIdx.x * blockDim.x + threadIdx.x;
  if (e < NE) {
    int d = ei[NE + e];
    int pos = atomicAdd(&cursor[d], 1);
    srcs[pos] = ei[e];
    float4 a0 = eattr4[(size_t)e * 4 + 0];
    float4 a1 = eattr4[(size_t)e * 4 + 1];
    float4 a2 = eattr4[(size_t)e * 4 + 2];
    float4 a3 = eattr4[(size_t)e * 4 + 3];
    ea_r[(size_t)pos * 4 + 0] = a0;
    ea_r[(size_t)pos * 4 + 1] = a1;
    ea_r[(size_t)pos * 4 + 2] = a2;
    ea_r[(size_t)pos * 4 + 3] = a3;
  }
}

// ---------------- split-bf16 conversion ----------------

__global__ void split_bf16(const float* __restrict__ src, unsigned short* __restrict__ hi,
                           unsigned short* __restrict__ lo, int n) {
  int i = blockIdx.x * 256 + threadIdx.x;
  if (i < n) {
    float v = src[i];
    unsigned short h = f2bf(v);
    hi[i] = h;
    lo[i] = f2bf(v - bf2f(h));
  }
}

__global__ void cat_split_T(const float* __restrict__ W1, const float* __restrict__ W2,
                            unsigned short* __restrict__ hi, unsigned short* __restrict__ lo,
                            int N0, int K, int total) {
  int i = blockIdx.x * 256 + threadIdx.x;
  if (i < total) {
    int n = i / K, k = i - n * K;
    float v = (n < N0) ? W1[k * N0 + n] : W2[k * N0 + n - N0];
    unsigned short h = f2bf(v);
    hi[i] = h;
    lo[i] = f2bf(v - bf2f(h));
  }
}

// ---------------- split-bf16 MFMA GEMM, B-resident-in-LDS, hi/lo-plane output ----------------

template<int K>
__global__ __launch_bounds__(256) void mfma_gemm_B(
    const unsigned short* __restrict__ Ah, const unsigned short* __restrict__ Al,
    const unsigned short* __restrict__ Bth, const unsigned short* __restrict__ Btl,
    unsigned short* __restrict__ Ch, unsigned short* __restrict__ Cl, int M, int N) {
  constexpr int BP = K + 24;
  __shared__ unsigned short Bsh[64 * BP], Bsl[64 * BP];
  int t = threadIdx.x;
  int wv = t >> 6, lane = t & 63;
  int quad = lane >> 4, mrow = lane & 15;
  int m0 = blockIdx.x * 64;
  int n0 = blockIdx.y * 64;

  for (int idx = t; idx < 64 * K / 8; idx += 256) {
    int n = idx / (K / 8), seg = (idx - n * (K / 8)) * 8;
    *(uint4*)(Bsh + n * BP + seg) = *(const uint4*)(Bth + (size_t)(n0 + n) * K + seg);
    *(uint4*)(Bsl + n * BP + seg) = *(const uint4*)(Btl + (size_t)(n0 + n) * K + seg);
  }
  __syncthreads();

  f32x4 acc[4];
#pragma unroll
  for (int i = 0; i < 4; ++i) acc[i] = (f32x4){0.f, 0.f, 0.f, 0.f};

  int arow = m0 + wv * 16 + mrow;
  if (arow >= M) arow = M - 1;
  const unsigned short* ap_h = Ah + (size_t)arow * K + quad * 8;
  const unsigned short* ap_l = Al + (size_t)arow * K + quad * 8;

  for (int ks = 0; ks < K; ks += 32) {
    bf16x8 ah = *(const bf16x8*)(ap_h + ks);
    bf16x8 al = *(const bf16x8*)(ap_l + ks);
#pragma unroll
    for (int nt = 0; nt < 4; ++nt) {
      bf16x8 bh = *(const bf16x8*)(Bsh + (nt * 16 + mrow) * BP + ks + quad * 8);
      bf16x8 bl = *(const bf16x8*)(Bsl + (nt * 16 + mrow) * BP + ks + quad * 8);
      acc[nt] = __builtin_amdgcn_mfma_f32_16x16x32_bf16(ah, bh, acc[nt], 0, 0, 0);
      acc[nt] = __builtin_amdgcn_mfma_f32_16x16x32_bf16(ah, bl, acc[nt], 0, 0, 0);
      acc[nt] = __builtin_amdgcn_mfma_f32_16x16x32_bf16(al, bh, acc[nt], 0, 0, 0);
    }
  }
#pragma unroll
  for (int nt = 0; nt < 4; ++nt)
#pragma unroll
    for (int r = 0; r < 4; ++r) {
      int row = m0 + wv * 16 + quad * 4 + r;
      if (row < M) {
        float f = acc[nt][r];
        unsigned short h = f2bf(f);
        size_t o = (size_t)row * N + n0 + nt * 16 + mrow;
        Ch[o] = h;
        Cl[o] = f2bf(f - bf2f(h));
      }
    }
}

// ---------------- helpers ----------------

__device__ __forceinline__ void ea_fma(float4& v, const float4 ea, const float4* w) {
  v.x += ea.x * w[0].x + ea.y * w[1].x + ea.z * w[2].x + ea.w * w[3].x;
  v.y += ea.x * w[0].y + ea.y * w[1].y + ea.z * w[2].y + ea.w * w[3].y;
  v.z += ea.x * w[0].z + ea.y * w[1].z + ea.z * w[2].z + ea.w * w[3].z;
  v.w += ea.x * w[0].w + ea.y * w[1].w + ea.z * w[2].w + ea.w * w[3].w;
}

__device__ __forceinline__ void leaky4(float4& v) {
  v.x = (v.x > 0.f) ? v.x : 0.2f * v.x;
  v.y = (v.y > 0.f) ? v.y : 0.2f * v.y;
  v.z = (v.z > 0.f) ? v.z : 0.2f * v.z;
  v.w = (v.w > 0.f) ? v.w : 0.2f * v.w;
}

// ---------------- fused edge-logit + aggregation, layer 1 ----------------
// Plain-sum softmax (exp bound-safe: logit ~ N(0,2.3), max ~8 << 88) makes the
// accumulate order-free, so el+agg fuse: one xl gather per edge instead of two.
// Wave per node; lane = (head, 4-ch); we/att/xr loaded once per node (same
// amortization as el1's 16-edge ownership); proven 2-edge unroll for ILP.

__global__ __launch_bounds__(256) void fused1(
    const int* __restrict__ srcs, const int* __restrict__ row_ptr,
    const float4* __restrict__ ea_r, const unsigned short* __restrict__ xh,
    const float* __restrict__ We, const float* __restrict__ att,
    const float* __restrict__ bias, unsigned short* __restrict__ h_hi,
    unsigned short* __restrict__ h_lo) {
  int w = threadIdx.x >> 6, lane = threadIdx.x & 63;
  int n = blockIdx.x * 4 + w;
  int col = (lane >> 4) * 64 + (lane & 15) * 4;
  float4 we[16];
#pragma unroll
  for (int k = 0; k < 16; ++k) we[k] = *(const float4*)(We + k * 256 + col);
  float4 at = *(const float4*)(att + col);
  float4 xr4 = ld_bf4(xh + (size_t)n * 512 + 256 + col);
  int beg = row_ptr[n], end = row_ptr[n + 1];

  float d0 = 0.f, d1 = 0.f;
  float4 a0 = {0, 0, 0, 0}, a1 = {0, 0, 0, 0};
  int i = beg;
  for (; i + 2 <= end; i += 2) {
    int s0 = srcs[i], s1 = srcs[i + 1];
    float4 xa = ld_bf4(xh + (size_t)s0 * 512 + col);
    float4 xb = ld_bf4(xh + (size_t)s1 * 512 + col);
    const float4* ep = ea_r + (size_t)i * 4;
    float4 p0 = ep[0], p1 = ep[1], p2 = ep[2], p3 = ep[3];
    float4 q0 = ep[4], q1 = ep[5], q2 = ep[6], q3 = ep[7];
    float4 v0, v1;
    v0.x = xa.x + xr4.x; v0.y = xa.y + xr4.y; v0.z = xa.z + xr4.z; v0.w = xa.w + xr4.w;
    v1.x = xb.x + xr4.x; v1.y = xb.y + xr4.y; v1.z = xb.z + xr4.z; v1.w = xb.w + xr4.w;
    ea_fma(v0, p0, we + 0); ea_fma(v0, p1, we + 4);
    ea_fma(v0, p2, we + 8); ea_fma(v0, p3, we + 12);
    ea_fma(v1, q0, we + 0); ea_fma(v1, q1, we + 4);
    ea_fma(v1, q2, we + 8); ea_fma(v1, q3, we + 12);
    leaky4(v0); leaky4(v1);
    float sA = at.x * v0.x + at.y * v0.y + at.z * v0.z + at.w * v0.w;
    float sB = at.x * v1.x + at.y * v1.y + at.z * v1.z + at.w * v1.w;
#pragma unroll
    for (int off = 8; off >= 1; off >>= 1) {  // reduce within 16-lane head group
      sA += __shfl_xor(sA, off);
      sB += __shfl_xor(sB, off);
    }
    float pA = __expf(sA), pB = __expf(sB);
    d0 += pA;
    a0.x += pA * xa.x; a0.y += pA * xa.y; a0.z += pA * xa.z; a0.w += pA * xa.w;
    d1 += pB;
    a1.x += pB * xb.x; a1.y += pB * xb.y; a1.z += pB * xb.z; a1.w += pB * xb.w;
  }
  if (i < end) {
    int s0 = srcs[i];
    float4 xa = ld_bf4(xh + (size_t)s0 * 512 + col);
    const float4* ep = ea_r + (size_t)i * 4;
    float4 p0 = ep[0], p1 = ep[1], p2 = ep[2], p3 = ep[3];
    float4 v0;
    v0.x = xa.x + xr4.x; v0.y = xa.y + xr4.y; v0.z = xa.z + xr4.z; v0.w = xa.w + xr4.w;
    ea_fma(v0, p0, we + 0); ea_fma(v0, p1, we + 4);
    ea_fma(v0, p2, we + 8); ea_fma(v0, p3, we + 12);
    leaky4(v0);
    float sA = at.x * v0.x + at.y * v0.y + at.z * v0.z + at.w * v0.w;
#pragma unroll
    for (int off = 8; off >= 1; off >>= 1) sA += __shfl_xor(sA, off);
    float pA = __expf(sA);
    d0 += pA;
    a0.x += pA * xa.x; a0.y += pA * xa.y; a0.z += pA * xa.z; a0.w += pA * xa.w;
  }
  float D = d0 + d1;
  float4 A;
  A.x = a0.x + a1.x; A.y = a0.y + a1.y; A.z = a0.z + a1.z; A.w = a0.w + a1.w;
  bool has = end > beg;
  float rd = has ? 1.f / D : 0.f;
  float4 b4 = *(const float4*)(bias + col);
  float4 o;
  o.x = A.x * rd + b4.x;
  o.y = A.y * rd + b4.y;
  o.z = A.z * rd + b4.z;
  o.w = A.w * rd + b4.w;
  o.x = (o.x > 0.f) ? o.x : (__expf(o.x) - 1.f);
  o.y = (o.y > 0.f) ? o.y : (__expf(o.y) - 1.f);
  o.z = (o.z > 0.f) ? o.z : (__expf(o.z) - 1.f);
  o.w = (o.w > 0.f) ? o.w : (__expf(o.w) - 1.f);
  ushort4 oh, ol;
  oh.x = f2bf(o.x); ol.x = f2bf(o.x - bf2f(oh.x));
  oh.y = f2bf(o.y); ol.y = f2bf(o.y - bf2f(oh.y));
  oh.z = f2bf(o.z); ol.z = f2bf(o.z - bf2f(oh.z));
  oh.w = f2bf(o.w); ol.w = f2bf(o.w - bf2f(oh.w));
  *(ushort4*)(h_hi + (size_t)n * 256 + col) = oh;
  *(ushort4*)(h_lo + (size_t)n * 256 + col) = ol;
}

// ---------------- fused edge-logit + aggregation, layer 2 (H=1, C=64) ----------------
// Wave per node; lane = channel; full-wave 6-round butterfly; fp32 output.

__global__ __launch_bounds__(256) void fused2(
    const int* __restrict__ srcs, const int* __restrict__ row_ptr,
    const float4* __restrict__ ea_r, const unsigned short* __restrict__ xh,
    const float* __restrict__ We, const float* __restrict__ att,
    const float* __restrict__ bias, float* __restrict__ out) {
  int w = threadIdx.x >> 6, lane = threadIdx.x & 63;
  int n = blockIdx.x * 4 + w;
  float we[16];
#pragma unroll
  for (int k = 0; k < 16; ++k) we[k] = We[k * 64 + lane];
  float at = att[lane];
  float xr = bf2f(xh[(size_t)n * 128 + 64 + lane]);
  int beg = row_ptr[n], end = row_ptr[n + 1];

  float d0 = 0.f, d1 = 0.f, a0 = 0.f, a1 = 0.f;
  int i = beg;
  for (; i + 2 <= end; i += 2) {
    int s0 = srcs[i], s1 = srcs[i + 1];
    float x0 = bf2f(xh[(size_t)s0 * 128 + lane]);
    float x1 = bf2f(xh[(size_t)s1 * 128 + lane]);
    const float4* ep = ea_r + (size_t)i * 4;
    float4 p0 = ep[0], p1 = ep[1], p2 = ep[2], p3 = ep[3];
    float4 q0 = ep[4], q1 = ep[5], q2 = ep[6], q3 = ep[7];
    float v0 = x0 + xr, v1 = x1 + xr;
    v0 += p0.x * we[0] + p0.y * we[1] + p0.z * we[2] + p0.w * we[3];
    v0 += p1.x * we[4] + p1.y * we[5] + p1.z * we[6] + p1.w * we[7];
    v0 += p2.x * we[8] + p2.y * we[9] + p2.z * we[10] + p2.w * we[11];
    v0 += p3.x * we[12] + p3.y * we[13] + p3.z * we[14] + p3.w * we[15];
    v1 += q0.x * we[0] + q0.y * we[1] + q0.z * we[2] + q0.w * we[3];
    v1 += q1.x * we[4] + q1.y * we[5] + q1.z * we[6] + q1.w * we[7];
    v1 += q2.x * we[8] + q2.y * we[9] + q2.z * we[10] + q2.w * we[11];
    v1 += q3.x * we[12] + q3.y * we[13] + q3.z * we[14] + q3.w * we[15];
    v0 = (v0 > 0.f) ? v0 : 0.2f * v0;
    v1 = (v1 > 0.f) ? v1 : 0.2f * v1;
    float sA = at * v0, sB = at * v1;
#pragma unroll
    for (int off = 32; off >= 1; off >>= 1) {
      sA += __shfl_xor(sA, off);
      sB += __shfl_xor(sB, off);
    }
    float pA = __expf(sA), pB = __expf(sB);
    d0 += pA; a0 += pA * x0;
    d1 += pB; a1 += pB * x1;
  }
  if (i < end) {
    int s0 = srcs[i];
    float x0 = bf2f(xh[(size_t)s0 * 128 + lane]);
    const float4* ep = ea_r + (size_t)i * 4;
    float4 p0 = ep[0], p1 = ep[1], p2 = ep[2], p3 = ep[3];
    float v0 = x0 + xr;
    v0 += p0.x * we[0] + p0.y * we[1] + p0.z * we[2] + p0.w * we[3];
    v0 += p1.x * we[4] + p1.y * we[5] + p1.z * we[6] + p1.w * we[7];
    v0 += p2.x * we[8] + p2.y * we[9] + p2.z * we[10] + p2.w * we[11];
    v0 += p3.x * we[12] + p3.y * we[13] + p3.z * we[14] + p3.w * we[15];
    v0 = (v0 > 0.f) ? v0 : 0.2f * v0;
    float sA = at * v0;
#pragma unroll
    for (int off = 32; off >= 1; off >>= 1) sA += __shfl_xor(sA, off);
    float pA = __expf(sA);
    d0 += pA; a0 += pA * x0;
  }
  float D = d0 + d1, A = a0 + a1;
  bool has = end > beg;
  float o = (has ? A / D : 0.f) + bias[lane];
  out[(size_t)n * 64 + lane] = o;
}

// ---------------- launch ----------------

extern "C" void kernel_launch(void* const* d_in, const int* in_sizes, int n_in,
                              void* d_out, int out_size, void* d_ws, size_t ws_size,
                              hipStream_t stream) {
  const float* x    = (const float*)d_in[0];
  const int*   ei   = (const int*)  d_in[1];
  const float* eatt = (const float*)d_in[2];
  const float* Wl1  = (const float*)d_in[3];
  const float* Wr1  = (const float*)d_in[4];
  const float* We1  = (const float*)d_in[5];
  const float* att1 = (const float*)d_in[6];
  const float* b1   = (const float*)d_in[7];
  const float* Wl2  = (const float*)d_in[8];
  const float* Wr2  = (const float*)d_in[9];
  const float* We2  = (const float*)d_in[10];
  const float* att2 = (const float*)d_in[11];
  const float* b2   = (const float*)d_in[12];
  float* out = (float*)d_out;

  char* wsb = (char*)d_ws;
  size_t off = 0;
  auto alloc = [&](size_t bytes) {
    char* p = wsb + off;
    off += (bytes + 255) & ~(size_t)255;
    return p;
  };
  int* counts    = (int*)alloc((size_t)NN * 4);
  int* tmp       = (int*)alloc((size_t)NN * 4);
  int* bsum      = (int*)alloc(32 * 4);
  int* row_ptr   = (int*)alloc((size_t)(NN + 1) * 4);
  int* cursor    = (int*)alloc((size_t)NN * 4);
  int* srcs      = (int*)alloc((size_t)NE * 4);
  float4* ea_r   = (float4*)alloc((size_t)NE * 16 * 4);
  unsigned short* x_hi  = (unsigned short*)alloc((size_t)NN * 128 * 2);
  unsigned short* x_lo  = (unsigned short*)alloc((size_t)NN * 128 * 2);
  unsigned short* W1th  = (unsigned short*)alloc((size_t)512 * 128 * 2);
  unsigned short* W1tl  = (unsigned short*)alloc((size_t)512 * 128 * 2);
  unsigned short* W2th  = (unsigned short*)alloc((size_t)128 * 256 * 2);
  unsigned short* W2tl  = (unsigned short*)alloc((size_t)128 * 256 * 2);
  unsigned short* h_hi  = (unsigned short*)alloc((size_t)NN * 256 * 2);
  unsigned short* h_lo  = (unsigned short*)alloc((size_t)NN * 256 * 2);
  unsigned short* x1h   = (unsigned short*)alloc((size_t)NN * 512 * 2);
  unsigned short* x1l   = (unsigned short*)alloc((size_t)NN * 512 * 2);
  unsigned short* x2h   = (unsigned short*)alloc((size_t)NN * 128 * 2);
  unsigned short* x2l   = (unsigned short*)alloc((size_t)NN * 128 * 2);

  // CSR by destination (+ srcs + edge_attr reorder)
  zero_i32<<<(NN + 255) / 256, 256, 0, stream>>>(counts, NN);
  count_dst<<<(NE + 255) / 256, 256, 0, stream>>>(ei, counts);
  scan_local<<<(NN + 1023) / 1024, 1024, 0, stream>>>(counts, tmp, bsum);
  scan_bsum<<<1, 64, 0, stream>>>(bsum, (NN + 1023) / 1024);
  scan_finish<<<(NN + 255) / 256, 256, 0, stream>>>(counts, tmp, bsum, row_ptr, cursor);
  scatter_edges<<<(NE + 255) / 256, 256, 0, stream>>>(ei, (const float4*)eatt, cursor,
                                                      srcs, ea_r);

  // split-bf16 conversions (W transposed for the B-resident GEMM)
  split_bf16<<<(NN * 128 + 255) / 256, 256, 0, stream>>>(x, x_hi, x_lo, NN * 128);
  cat_split_T<<<(512 * 128 + 255) / 256, 256, 0, stream>>>(Wl1, Wr1, W1th, W1tl, 256, 128,
                                                           512 * 128);
  cat_split_T<<<(128 * 256 + 255) / 256, 256, 0, stream>>>(Wl2, Wr2, W2th, W2tl, 64, 256,
                                                           128 * 256);

  // layer 1
  mfma_gemm_B<128><<<dim3((NN + 63) / 64, 8), 256, 0, stream>>>(
      x_hi, x_lo, W1th, W1tl, x1h, x1l, NN, 512);
  fused1<<<NN / 4, 256, 0, stream>>>(srcs, row_ptr, ea_r, x1h, We1, att1, b1, h_hi, h_lo);

  // layer 2
  mfma_gemm_B<256><<<dim3((NN + 63) / 64, 2), 256, 0, stream>>>(
      h_hi, h_lo, W2th, W2tl, x2h, x2l, NN, 128);
  fused2<<<NN / 4, 256, 0, stream>>>(srcs, row_ptr, ea_r, x2h, We2, att2, b2, out);
}